// Round 12
// baseline (89.614 us; speedup 1.0000x reference)
//
#include <hip/hip_runtime.h>
#include <math.h>

// out[n,o] = exp(A)*cos(B)
//   A = sum_i ln(R)*Wr - K*Wi ;  B = sum_i ln(R)*Wi + K*Wr
//   R = 1 + g*(|x|-1),  K = pi*(x<0)*g,  g = clip(G,0,1)
// n=8192, i=o=128.
//
// R12: o-PAIRING. Each thread owns o64 and o64+64 -> the 4 broadcast
// ds_read_b128 x-frags per iter feed 16 elems instead of 8 (LDS instrs and
// latency chains per elem HALVED at equal VALU/elem and logs/elem -- the one
// variable untested: R8 traded LDS for VALU and lost by the VALU add).
// Block = 512 thr = (o64:64)x(q:8 i-eighths), RPB=8, IQ=16; 1024 blocks x
// 8 waves = 8/SIMD, same as R6. Iter split into two half-row groups so only
// 8 frag VGPRs live at once (~58 total, fits 64-VGPR/8-wave budget).
// Epilogue: 8-plane q-reduce, 32 KB LDS overlay, A then B.

#define NROWS 8192
#define DIM   128
#define RPB   8
#define NT    512
#define IQ    16
#define PI_F  3.14159265358979323846f
#define LN2_F 0.69314718055994530942f

typedef float v2f __attribute__((ext_vector_type(2)));

static __device__ __forceinline__ v2f vfma2(v2f a, v2f b, v2f c) {
    return __builtin_elementwise_fma(a, b, c);
}

// wq[i*DIM+o] = (ln2*wr, ln2*wi, g, g/ln2). One-time, 64 blocks.
__global__ __launch_bounds__(256) void prep_w(
    const float* __restrict__ Wr, const float* __restrict__ Wi,
    const float* __restrict__ G, float4* __restrict__ wq)
{
    int t = blockIdx.x * 256 + threadIdx.x;
    if (t < DIM * DIM) {
        float g  = fminf(fmaxf(G[t], 0.0f), 1.0f);
        wq[t] = make_float4(LN2_F * Wr[t], LN2_F * Wi[t], g, g * (1.0f / LN2_F));
    }
}

template <bool PACKED>
__global__ __launch_bounds__(NT, 8) void main_kernel(
    const float* __restrict__ x, const float4* __restrict__ wq,
    const float* __restrict__ Wr, const float* __restrict__ Wi,
    const float* __restrict__ G, float* __restrict__ out)
{
    // 32 KB. Main loop: am1 plane + ps plane [DIM][RPB] (first 8 KB).
    // Epilogue overlay: one partial buffer [8][RPB][DIM] (32 KB), A then B.
    __shared__ float sbuf[8 * RPB * DIM];
    float* am1p = sbuf;               // [DIM][RPB]
    float* psp  = sbuf + DIM * RPB;   // [DIM][RPB]

    const int tid   = threadIdx.x;
    const int o64   = tid & 63;            // o-low; thread owns o64 and o64+64
    const int q     = tid >> 6;            // i-eighth 0..7
    const int nbase = blockIdx.x * RPB;
    const float* xb = x + (size_t)nbase * DIM;

    // Stage x tile (1024 floats): float2 coalesced read, SoA scatter.
    {
        float2 v = ((const float2*)xb)[tid];
        int e = tid * 2;
        int i = e & (DIM - 1), r = e >> 7;
        am1p[i * RPB + r]       = fabsf(v.x) - 1.0f;
        am1p[(i + 1) * RPB + r] = fabsf(v.y) - 1.0f;
        psp[i * RPB + r]        = (v.x < 0.0f) ? PI_F : 0.0f;
        psp[(i + 1) * RPB + r]  = (v.y < 0.0f) ? PI_F : 0.0f;
    }
    __syncthreads();

    // acc[o-half][pair]: pair p covers rows 2p,2p+1.
    v2f aA0[4], aB0[4], aA1[4], aB1[4];
#pragma unroll
    for (int p = 0; p < 4; ++p) {
        aA0[p] = (v2f){0.f, 0.f}; aB0[p] = (v2f){0.f, 0.f};
        aA1[p] = (v2f){0.f, 0.f}; aB1[p] = (v2f){0.f, 0.f};
    }

    const int ibase = q * IQ;
#pragma unroll 2
    for (int ii = 0; ii < IQ; ++ii) {
        const int i = ibase + ii;
        float wrl0, wil0, g0, gq0, wrl1, wil1, g1, gq1;
        if (PACKED) {
            float4 w0 = wq[i * DIM + o64];
            float4 w1 = wq[i * DIM + o64 + 64];
            wrl0 = w0.x; wil0 = w0.y; g0 = w0.z; gq0 = w0.w;
            wrl1 = w1.x; wil1 = w1.y; g1 = w1.z; gq1 = w1.w;
        } else {
            g0   = fminf(fmaxf(G[i * DIM + o64], 0.0f), 1.0f);
            wrl0 = LN2_F * Wr[i * DIM + o64];
            wil0 = LN2_F * Wi[i * DIM + o64];
            gq0  = g0 * (1.0f / LN2_F);
            g1   = fminf(fmaxf(G[i * DIM + o64 + 64], 0.0f), 1.0f);
            wrl1 = LN2_F * Wr[i * DIM + o64 + 64];
            wil1 = LN2_F * Wi[i * DIM + o64 + 64];
            gq1  = g1 * (1.0f / LN2_F);
        }
        const float ngwi0 = -gq0 * wil0, gwr0 = gq0 * wrl0;
        const float ngwi1 = -gq1 * wil1, gwr1 = gq1 * wrl1;

        const float4* a4 = (const float4*)(am1p + i * RPB);
        const float4* p4 = (const float4*)(psp  + i * RPB);

#define RP(mx, my, sx, sy, g_, wrl_, wil_, ngwi_, gwr_, accA, accB)         \
        do {                                                                \
            v2f t2 = vfma2((v2f){mx, my}, (v2f){g_, g_}, (v2f){1.f, 1.f});  \
            v2f l2 = { __log2f(t2.x), __log2f(t2.y) };                      \
            v2f s2 = {sx, sy};                                              \
            accA = vfma2(l2, (v2f){wrl_, wrl_},                             \
                         vfma2(s2, (v2f){ngwi_, ngwi_}, accA));             \
            accB = vfma2(l2, (v2f){wil_, wil_},                             \
                         vfma2(s2, (v2f){gwr_, gwr_},  accB));              \
        } while (0)

        {   // rows 0..3 (frag regs die before second half)
            float4 a = a4[0], s = p4[0];
            RP(a.x, a.y, s.x, s.y, g0, wrl0, wil0, ngwi0, gwr0, aA0[0], aB0[0]);
            RP(a.z, a.w, s.z, s.w, g0, wrl0, wil0, ngwi0, gwr0, aA0[1], aB0[1]);
            RP(a.x, a.y, s.x, s.y, g1, wrl1, wil1, ngwi1, gwr1, aA1[0], aB1[0]);
            RP(a.z, a.w, s.z, s.w, g1, wrl1, wil1, ngwi1, gwr1, aA1[1], aB1[1]);
        }
        {   // rows 4..7
            float4 a = a4[1], s = p4[1];
            RP(a.x, a.y, s.x, s.y, g0, wrl0, wil0, ngwi0, gwr0, aA0[2], aB0[2]);
            RP(a.z, a.w, s.z, s.w, g0, wrl0, wil0, ngwi0, gwr0, aA0[3], aB0[3]);
            RP(a.x, a.y, s.x, s.y, g1, wrl1, wil1, ngwi1, gwr1, aA1[2], aB1[2]);
            RP(a.z, a.w, s.z, s.w, g1, wrl1, wil1, ngwi1, gwr1, aA1[3], aB1[3]);
        }
#undef RP
    }

    // Epilogue: 8-plane q-reduce via one 32 KB buffer, A then B.
    float* pP = sbuf;                        // [8][RPB][DIM]
    const int c = tid * 2;
    const int r = c >> 7, oo = c & (DIM - 1);

    __syncthreads();   // all waves done reading planes
#pragma unroll
    for (int p = 0; p < 4; ++p) {
        pP[q * (RPB * DIM) + (2 * p) * DIM + o64]          = aA0[p].x;
        pP[q * (RPB * DIM) + (2 * p + 1) * DIM + o64]      = aA0[p].y;
        pP[q * (RPB * DIM) + (2 * p) * DIM + o64 + 64]     = aA1[p].x;
        pP[q * (RPB * DIM) + (2 * p + 1) * DIM + o64 + 64] = aA1[p].y;
    }
    __syncthreads();
    v2f A = {0.f, 0.f};
#pragma unroll
    for (int qq = 0; qq < 8; ++qq)
        A += *(const v2f*)&pP[qq * (RPB * DIM) + r * DIM + oo];
    __syncthreads();   // before overwriting with B partials
#pragma unroll
    for (int p = 0; p < 4; ++p) {
        pP[q * (RPB * DIM) + (2 * p) * DIM + o64]          = aB0[p].x;
        pP[q * (RPB * DIM) + (2 * p + 1) * DIM + o64]      = aB0[p].y;
        pP[q * (RPB * DIM) + (2 * p) * DIM + o64 + 64]     = aB1[p].x;
        pP[q * (RPB * DIM) + (2 * p + 1) * DIM + o64 + 64] = aB1[p].y;
    }
    __syncthreads();
    v2f B = {0.f, 0.f};
#pragma unroll
    for (int qq = 0; qq < 8; ++qq)
        B += *(const v2f*)&pP[qq * (RPB * DIM) + r * DIM + oo];

    float2 res;
    res.x = __expf(A.x) * __cosf(B.x);
    res.y = __expf(A.y) * __cosf(B.y);
    *(float2*)&out[(size_t)(nbase + r) * DIM + oo] = res;
}

extern "C" void kernel_launch(void* const* d_in, const int* in_sizes, int n_in,
                              void* d_out, int out_size, void* d_ws, size_t ws_size,
                              hipStream_t stream) {
    const float* x  = (const float*)d_in[0];
    const float* Wr = (const float*)d_in[1];
    const float* Wi = (const float*)d_in[2];
    const float* G  = (const float*)d_in[3];
    float* out = (float*)d_out;

    const size_t wq_bytes = (size_t)DIM * DIM * sizeof(float4);   // 256 KB
    if (ws_size >= wq_bytes) {
        float4* wq = (float4*)d_ws;
        prep_w<<<(DIM * DIM + 255) / 256, 256, 0, stream>>>(Wr, Wi, G, wq);
        main_kernel<true><<<NROWS / RPB, NT, 0, stream>>>(x, wq,
                                                          nullptr, nullptr, nullptr, out);
    } else {
        main_kernel<false><<<NROWS / RPB, NT, 0, stream>>>(x, nullptr,
                                                           Wr, Wi, G, out);
    }
}